// Round 10
// baseline (145.918 us; speedup 1.0000x reference)
//
#include <hip/hip_runtime.h>
#include <math.h>

#define N_NODES 20000
#define N_EDGES 160000

typedef unsigned short ushort_t;
typedef __attribute__((ext_vector_type(8))) short short8v;   // 8 bf16 = 4 VGPR
typedef __attribute__((ext_vector_type(4))) float f32x4;
typedef __attribute__((ext_vector_type(8))) float f32x8;

// ---- workspace layout (float offsets) ----
#define WS_We0  0         // [8][16] f32
#define WS_b0m  128       // [16]
#define WS_W0   256       // [80][128] f32 (folded)
#define WS_b0   10496     // [128]
#define WS_We1  10624     // [8][128] f32
#define WS_b1m  11648     // [128]
#define WS_b1   11776     // [128]
#define WS_WP1  11904     // bf16 frags 81920 -> 40960 f  (B for gemm1, K=640)
#define WS_WPTU 52864     // bf16 frags 32768 -> 16384 f  (B for t1/u1)
#define WS_t0   69248     // f32 [20000][16]
#define WS_u0   389248    // f32 [20000][16]
#define WS_h0b  709248    // bf16 [20000][128] = 1,280,000 f
#define WS_t1   1989248   // f32 [20000][128]
#define WS_u1   4549248   // bf16 [20000][128] (u1b)
#define WS_A0   7109248   // f32 [20000][80]  (dead after gemm0 phase)
#define WS_A1   7109248   // bf16 [20000][512] OVERLAYS A0; ends 12,229,248
// end 12,229,248 f = 48.9 MB

__device__ inline ushort_t f2bf(float f) {   // round-to-nearest-even f32->bf16
    union { float f; unsigned u; } v; v.f = f;
    unsigned r = v.u + 0x7FFFu + ((v.u >> 16) & 1u);
    return (ushort_t)(r >> 16);
}
__device__ inline float bf2f(short s) {
    union { unsigned u; float f; } v; v.u = ((unsigned)(ushort_t)s) << 16; return v.f;
}

// ================= phase 0: weight folds + direct frag packing + t0/u0 ================
__device__ __attribute__((noinline)) void prep_item(
    int tid, const float* __restrict__ x,
    const float* __restrict__ ew0, const float* __restrict__ eb0,
    const float* __restrict__ pw0, const float* __restrict__ pb0,
    const float* __restrict__ qw0, const float* __restrict__ qb0,
    const float* __restrict__ lw0, const float* __restrict__ lb0,
    const float* __restrict__ ew1, const float* __restrict__ eb1,
    const float* __restrict__ pw1, const float* __restrict__ pb1,
    const float* __restrict__ qw1, const float* __restrict__ qb1,
    const float* __restrict__ lw1, const float* __restrict__ lb1,
    float* __restrict__ ws)
{
    if (tid < 81920) {                 // W1 fold -> WP1 bf16 frag: [640][128]
        int r = tid >> 7, o = tid & 127;
        float acc = 0.f;
        for (int h = 0; h < 128; ++h) {
            float qr;
            if (r < 128) qr = qw1[r*128 + h];
            else {
                int s = r - 128;
                qr = qw1[(128+s)*128+h] + qw1[(640+s)*128+h] + qw1[(1152+s)*128+h];
            }
            acc += qr * lw1[h*128 + o];
        }
        int ct = o >> 4, ks = r >> 5;
        int l = (o & 15) | (((r >> 3) & 3) << 4);
        ((ushort_t*)(ws + WS_WP1))[(size_t)(((ct*20 + ks)*64) + l)*8 + (r & 7)] = f2bf(acc);
    } else if (tid < 82048) {          // b1 = qb1@lw1 + lb1
        int o = tid - 81920;
        float acc = lb1[o];
        for (int h = 0; h < 128; ++h) acc += qb1[h] * lw1[h*128 + o];
        ws[WS_b1 + o] = acc;
    } else if (tid < 92288) {          // W0 fold f32 [80][128]
        int idx = tid - 82048; int r = idx >> 7, o = idx & 127;
        float acc = 0.f;
        for (int h = 0; h < 128; ++h) {
            float qr;
            if (r < 16) qr = qw0[r*128 + h];
            else {
                int s = r - 16;
                qr = qw0[(16+s)*128+h] + qw0[(80+s)*128+h] + qw0[(144+s)*128+h];
            }
            acc += qr * lw0[h*128 + o];
        }
        ws[WS_W0 + idx] = acc;
    } else if (tid < 92416) {          // b0 = qb0@lw0 + lb0
        int o = tid - 92288;
        float acc = lb0[o];
        for (int h = 0; h < 128; ++h) acc += qb0[h] * lw0[h*128 + o];
        ws[WS_b0 + o] = acc;
    } else if (tid < 93440) {          // We1 = ew1 @ pw1_c  [8][128] f32
        int idx = tid - 92416; int c = idx >> 7, f = idx & 127;
        float acc = 0.f;
        for (int k = 0; k < 128; ++k) acc += ew1[c*128 + k] * pw1[(256+k)*128 + f];
        ws[WS_We1 + idx] = acc;
    } else if (tid < 93568) {          // b1m = eb1@pw1_c + pb1
        int f = tid - 93440;
        float acc = pb1[f];
        for (int k = 0; k < 128; ++k) acc += eb1[k] * pw1[(256+k)*128 + f];
        ws[WS_b1m + f] = acc;
    } else if (tid < 93696) {          // We0 = ew0 @ pw0_c  [8][16]
        int idx = tid - 93568; int c = idx >> 4, f = idx & 15;
        float acc = 0.f;
        for (int k = 0; k < 16; ++k) acc += ew0[c*16 + k] * pw0[(32+k)*16 + f];
        ws[WS_We0 + idx] = acc;
    } else if (tid < 93712) {          // b0m = eb0@pw0_c + pb0
        int f = tid - 93696;
        float acc = pb0[f];
        for (int k = 0; k < 16; ++k) acc += eb0[k] * pw0[(32+k)*16 + f];
        ws[WS_b0m + f] = acc;
    } else if (tid < 126480) {         // WPTU direct pack from pw1 rows 0..255
        int idx = tid - 93712;
        int r = idx >> 7, o = idx & 127;
        int part = r >> 7, rk = r & 127;
        int ct = part*8 + (o >> 4);
        int l = (o & 15) | (((rk >> 3) & 3) << 4);
        ((ushort_t*)(ws + WS_WPTU))[(size_t)(((ct*4 + (rk >> 5))*64) + l)*8 + (rk & 7)]
            = f2bf(pw1[r*128 + o]);
    } else if (tid < 446480) {         // t0 = x @ pw0_a  [20000][16]
        int idx = tid - 126480; int i = idx >> 4, f = idx & 15;
        float acc = 0.f;
        for (int k = 0; k < 16; ++k) acc += x[i*16 + k] * pw0[k*16 + f];
        ws[WS_t0 + idx] = acc;
    } else if (tid < 766480) {         // u0 = x @ pw0_b  [20000][16]
        int idx = tid - 446480; int i = idx >> 4, f = idx & 15;
        float acc = 0.f;
        for (int k = 0; k < 16; ++k) acc += x[i*16 + k] * pw0[(16+k)*16 + f];
        ws[WS_u0 + idx] = acc;
    }
}

// ================= phase 1: layer-0 gather + aggregate -> A0 (f32)  [R8-proven] =================
__device__ __attribute__((noinline)) void agg0_tile(
    int tile, int t, const float* __restrict__ x, const float* __restrict__ ea,
    const int* __restrict__ src, float* __restrict__ ws)
{
    static __shared__ float ea_s0[16*8*8];   // [n][k][c]
    static __shared__ int   src_s0[16*8];
    static __shared__ float We0_s0[128];
    static __shared__ float b0m_s0[16];
    const int i0 = tile * 16;
    __syncthreads();            // LDS reuse guard

    for (int idx = t; idx < 1024; idx += 256) {
        int k = idx >> 7; int rem = idx & 127; int n = rem >> 3, c = rem & 7;
        ea_s0[(n*8 + k)*8 + c] = ea[(i0 + n + k*N_NODES)*8 + c];
    }
    if (t < 128) {
        int k = t >> 4, n = t & 15;
        src_s0[n*8 + k] = src[i0 + n + k*N_NODES];
        We0_s0[t] = ws[WS_We0 + t];
    }
    if (t < 16) b0m_s0[t] = ws[WS_b0m + t];
    __syncthreads();

    const int n = t >> 4, f = t & 15;
    const int i = i0 + n;
    float base = ws[WS_t0 + i*16 + f] + b0m_s0[f];
    float s = 0.f, q = 0.f, mx = -1e30f, mn = 1e30f;
    for (int k = 0; k < 8; ++k) {
        int sj = src_s0[n*8 + k];
        float m = base + ws[WS_u0 + sj*16 + f];
        #pragma unroll
        for (int c = 0; c < 8; ++c) m += ea_s0[(n*8+k)*8 + c] * We0_s0[c*16 + f];
        s += m; q += m*m; mx = fmaxf(mx, m); mn = fminf(mn, m);
    }
    float mean = s * 0.125f, mean2 = q * 0.125f;
    float sd = sqrtf(fmaxf(mean2 - mean*mean, 0.f) + 1e-5f);
    float* A0 = ws + WS_A0 + (size_t)i * 80;
    A0[f]      = x[i*16 + f];
    A0[16 + f] = mean;
    A0[32 + f] = mx;
    A0[48 + f] = mn;
    A0[64 + f] = sd;
}

// ================= phase 2: h0b = bf16(relu(LN(A0 @ W0 + b0)))  [R8-proven 32-row] =================
__device__ __attribute__((noinline)) void gemm0_tile(
    int tile, int t, const float* __restrict__ g0, const float* __restrict__ bln0,
    float* __restrict__ ws)
{
    static __shared__ float As[32][81];
    const int r0 = tile * 32;
    __syncthreads();            // orders prior global writes + LDS reuse
    const float* A = ws + WS_A0 + (size_t)r0 * 80;
    for (int idx = t; idx < 32*80; idx += 256) {
        int r = idx / 80, k = idx - r*80;
        As[r][k] = A[idx];
    }
    __syncthreads();
    const int tc = t & 31, tr = t >> 5;
    const int c0 = tc * 4;
    float acc[4][4] = {};
    const float* W = ws + WS_W0;
    #pragma unroll 4
    for (int k = 0; k < 80; ++k) {
        float4 b = *(const float4*)(W + k*128 + c0);
        #pragma unroll
        for (int rr = 0; rr < 4; ++rr) {
            float a = As[tr*4 + rr][k];
            acc[rr][0] += a*b.x; acc[rr][1] += a*b.y;
            acc[rr][2] += a*b.z; acc[rr][3] += a*b.w;
        }
    }
    float4 bias = *(const float4*)(ws + WS_b0 + c0);
    float4 g  = *(const float4*)(g0 + c0);
    float4 bb = *(const float4*)(bln0 + c0);
    ushort_t* h0b = (ushort_t*)(ws + WS_h0b);
    #pragma unroll
    for (int rr = 0; rr < 4; ++rr) {
        float v0 = acc[rr][0] + bias.x, v1 = acc[rr][1] + bias.y;
        float v2 = acc[rr][2] + bias.z, v3 = acc[rr][3] + bias.w;
        float sum = v0+v1+v2+v3;
        float sq  = v0*v0+v1*v1+v2*v2+v3*v3;
        #pragma unroll
        for (int off = 1; off < 32; off <<= 1) {
            sum += __shfl_xor(sum, off, 64);
            sq  += __shfl_xor(sq,  off, 64);
        }
        float mean = sum * (1.f/128.f);
        float var  = sq  * (1.f/128.f) - mean*mean;
        float rstd = rsqrtf(var + 1e-5f);
        ushort4 ob;
        ob.x = f2bf(fmaxf((v0-mean)*rstd*g.x + bb.x, 0.f));
        ob.y = f2bf(fmaxf((v1-mean)*rstd*g.y + bb.y, 0.f));
        ob.z = f2bf(fmaxf((v2-mean)*rstd*g.z + bb.z, 0.f));
        ob.w = f2bf(fmaxf((v3-mean)*rstd*g.w + bb.w, 0.f));
        *(ushort4*)(h0b + (size_t)(r0 + tr*4 + rr)*128 + c0) = ob;
    }
}

// ========== phase 3: t1 (f32) | u1 (bf16) half-tile = h0 @ pw1[a|b]  [R8-proven] ==========
__device__ __attribute__((noinline)) void tu1_half(
    int tile, int part, int lane, float* __restrict__ ws)
{
    const int rowbase = tile * 16;
    const ushort_t* h0b = (const ushort_t*)(ws + WS_h0b);
    const ushort_t* WP  = (const ushort_t*)(ws + WS_WPTU);
    const int lr = lane & 15, lk = lane >> 4;
    const size_t arow = rowbase + lr;
    f32x4 acc[8];
    #pragma unroll
    for (int c = 0; c < 8; ++c) acc[c] = (f32x4){0.f,0.f,0.f,0.f};

    #pragma unroll
    for (int ks = 0; ks < 4; ++ks) {
        short8v a = *(const short8v*)(h0b + arow*128 + ks*32 + lk*8);
        #pragma unroll
        for (int c = 0; c < 8; ++c) {
            short8v b = *(const short8v*)(WP + ((size_t)((part*8 + c)*4 + ks)*64 + lane)*8);
            acc[c] = __builtin_amdgcn_mfma_f32_16x16x32_bf16(a, b, acc[c], 0, 0, 0);
        }
    }
    if (part == 0) {                    // t1 stays f32
        float* t1 = ws + WS_t1;
        #pragma unroll
        for (int c = 0; c < 8; ++c) {
            int cb = c*16 + lr;
            #pragma unroll
            for (int r = 0; r < 4; ++r) {
                int row = rowbase + lk*4 + r;  // C/D: col=lane&15, row=(lane>>4)*4+reg
                t1[(size_t)row*128 + cb] = acc[c][r];
            }
        }
    } else {                            // u1 -> bf16
        ushort_t* u1b = (ushort_t*)(ws + WS_u1);
        #pragma unroll
        for (int c = 0; c < 8; ++c) {
            int cb = c*16 + lr;
            #pragma unroll
            for (int r = 0; r < 4; ++r) {
                int row = rowbase + lk*4 + r;
                u1b[(size_t)row*128 + cb] = f2bf(acc[c][r]);
            }
        }
    }
}

// ======== phase 4 (8 nodes, 128 thr): layer-1 aggregate -> A1 bf16  [value-proven R9] ========
__device__ __attribute__((noinline)) void agg1_tile128(
    int tile, int t, const float* __restrict__ ea, const int* __restrict__ src,
    float* __restrict__ ws)
{
    static __shared__ float ea_t[8*8*8];     // 512
    static __shared__ int   src_t[64];
    static __shared__ float We1_t[1024];
    static __shared__ float b1m_t[128];
    const int i0 = tile * 8;
    __syncthreads();            // LDS reuse guard

    for (int idx = t; idx < 512; idx += 128) {
        int k = idx >> 6; int rem = idx & 63; int n = rem >> 3, c = rem & 7;
        ea_t[(n*8 + k)*8 + c] = ea[(size_t)(i0 + n + k*N_NODES)*8 + c];
    }
    if (t < 64) {
        int k = t >> 3, n = t & 7;
        src_t[n*8 + k] = src[i0 + n + k*N_NODES];
    }
    for (int idx = t; idx < 1024; idx += 128) We1_t[idx] = ws[WS_We1 + idx];
    if (t < 128) b1m_t[t] = ws[WS_b1m + t];
    __syncthreads();

    const int n = t >> 4, f0 = (t & 15) * 8;
    const int i = i0 + n;
    const ushort_t* u1b = (const ushort_t*)(ws + WS_u1);
    float base[8], sm[8], sq[8], mx[8], mn[8];
    #pragma unroll
    for (int e = 0; e < 8; ++e) {
        base[e] = ws[WS_t1 + (size_t)i*128 + f0 + e] + b1m_t[f0 + e];
        sm[e] = 0.f; sq[e] = 0.f; mx[e] = -1e30f; mn[e] = 1e30f;
    }
    for (int k = 0; k < 8; ++k) {
        int sj = src_t[n*8 + k];
        short8v uv = *(const short8v*)(u1b + (size_t)sj*128 + f0);   // 16B gather
        float m[8];
        #pragma unroll
        for (int e = 0; e < 8; ++e) m[e] = base[e] + bf2f(uv[e]);
        #pragma unroll
        for (int c = 0; c < 8; ++c) {
            float a = ea_t[(n*8 + k)*8 + c];
            #pragma unroll
            for (int e = 0; e < 8; ++e) m[e] += a * We1_t[c*128 + f0 + e];
        }
        #pragma unroll
        for (int e = 0; e < 8; ++e) {
            sm[e] += m[e]; sq[e] += m[e]*m[e];
            mx[e] = fmaxf(mx[e], m[e]); mn[e] = fminf(mn[e], m[e]);
        }
    }
    ushort_t* A1 = (ushort_t*)(ws + WS_A1);
    short8v vm, vx, vn, vs;
    #pragma unroll
    for (int e = 0; e < 8; ++e) {
        float mean = sm[e]*0.125f, m2 = sq[e]*0.125f;
        float sd = sqrtf(fmaxf(m2 - mean*mean, 0.f) + 1e-5f);
        vm[e] = (short)f2bf(mean);
        vx[e] = (short)f2bf(mx[e]);
        vn[e] = (short)f2bf(mn[e]);
        vs[e] = (short)f2bf(sd);
    }
    size_t b = (size_t)i*512 + f0;
    *(short8v*)(A1 + b)       = vm;
    *(short8v*)(A1 + b + 128) = vx;
    *(short8v*)(A1 + b + 256) = vn;
    *(short8v*)(A1 + b + 384) = vs;
}

// ======================= args struct =======================
struct KArgs {
    const float *x, *ea; const int* src;
    const float *ew0,*eb0,*pw0,*pb0,*qw0,*qb0,*lw0,*lb0,*g0,*bl0;
    const float *ew1,*eb1,*pw1,*pb1,*qw1,*qb1,*lw1,*lb1,*g1,*bl1;
    const float *hw,*hb;
    float* ws; float* out;
};

// ============ launch 1: prep ============
__global__ __launch_bounds__(256) void k_prep(KArgs a) {
    int tid = blockIdx.x*256 + threadIdx.x;
    prep_item(tid, a.x, a.ew0, a.eb0, a.pw0, a.pb0, a.qw0, a.qb0, a.lw0, a.lb0,
              a.ew1, a.eb1, a.pw1, a.pb1, a.qw1, a.qb1, a.lw1, a.lb1, a.ws);
}

// ============ launch 2: agg0 x2 -> gemm0 -> tu1 x4 (32 rows/block)  [R8-proven verbatim] ============
__global__ __launch_bounds__(256) void k_mid(KArgs a) {
    const int b = blockIdx.x, t = threadIdx.x;
    agg0_tile(b*2,     t, a.x, a.ea, a.src, a.ws);
    agg0_tile(b*2 + 1, t, a.x, a.ea, a.src, a.ws);
    gemm0_tile(b, t, a.g0, a.bl0, a.ws);       // entry-sync orders A0 writes
    __syncthreads();                            // h0b global writes -> tu1 reads
    const int w = t >> 6;
    tu1_half(b*2 + (w >> 1), w & 1, t & 63, a.ws);
}

// ===== launch 3: 8 nodes/block, 128 thr: agg1 -> 2-wave col-split gemm1 + LN + head =====
// ALL reads block-local: A-fragment lanes lr>=8 re-read the block's OWN rows (lr&7);
// their D rows (8..15) are discarded. No intra-launch cross-block access anywhere.
__global__ __launch_bounds__(128, 4) void k_tail(KArgs a) {
    const int b = blockIdx.x, t = threadIdx.x;
    float* ws = a.ws;

    agg1_tile128(b, t, a.ea, a.src, ws);
    __syncthreads();                            // A1 global writes -> gemm1 reads (same block)

    static __shared__ float redS[2][16], redQ[2][16];
    static __shared__ f32x4 redP[16];
    const int w = t >> 6, lane = t & 63;
    const int lr = lane & 15, lk = lane >> 4;
    const int rowbase = b * 8;
    const int row = rowbase + (lr & 7);         // block-local duplicate rows for lr>=8
    const ushort_t* h0b = (const ushort_t*)(ws + WS_h0b);
    const ushort_t* A1  = (const ushort_t*)(ws + WS_A1);
    const ushort_t* WP  = (const ushort_t*)(ws + WS_WP1);

    f32x4 acc[4];
    #pragma unroll
    for (int c = 0; c < 4; ++c) acc[c] = (f32x4){0.f,0.f,0.f,0.f};

    #pragma unroll
    for (int kw = 0; kw < 4; ++kw) {            // K 0..127 from h0b
        short8v av = *(const short8v*)(h0b + (size_t)row*128 + kw*32 + lk*8);
        #pragma unroll
        for (int c = 0; c < 4; ++c) {
            int ct = w*4 + c;
            short8v bv = *(const short8v*)(WP + (size_t)((ct*20 + kw)*64 + lane)*8);
            acc[c] = __builtin_amdgcn_mfma_f32_16x16x32_bf16(av, bv, acc[c], 0, 0, 0);
        }
    }
    #pragma unroll 4
    for (int ks = 0; ks < 16; ++ks) {           // K 128..639 from A1 (own 8 rows only)
        short8v av = *(const short8v*)(A1 + (size_t)row*512 + ks*32 + lk*8);
        #pragma unroll
        for (int c = 0; c < 4; ++c) {
            int ct = w*4 + c;
            short8v bv = *(const short8v*)(WP + (size_t)((ct*20 + 4 + ks)*64 + lane)*8);
            acc[c] = __builtin_amdgcn_mfma_f32_16x16x32_bf16(av, bv, acc[c], 0, 0, 0);
        }
    }

    float bc[4], gc[4], bbc[4]; f32x4 hwc[4];
    #pragma unroll
    for (int c = 0; c < 4; ++c) {
        int col = (w*4 + c)*16 + lr;
        bc[c]  = ws[WS_b1 + col];
        gc[c]  = a.g1[col];
        bbc[c] = a.bl1[col];
        hwc[c] = *(const f32x4*)(a.hw + col*4);
    }

    // pass 1: per-wave partial LN sums over its 64 cols
    #pragma unroll
    for (int r = 0; r < 4; ++r) {
        float s = 0.f, q = 0.f;
        #pragma unroll
        for (int c = 0; c < 4; ++c) {
            float v = acc[c][r] + bc[c];
            s += v; q += v*v;
        }
        #pragma unroll
        for (int off = 1; off < 16; off <<= 1) {
            s += __shfl_xor(s, off, 64);
            q += __shfl_xor(q, off, 64);
        }
        if (lr == 0) { redS[w][lk*4 + r] = s; redQ[w][lk*4 + r] = q; }
    }
    __syncthreads();

    // pass 2: full LN + relu + head partial over own cols
    f32x4 poarr[4];
    #pragma unroll
    for (int r = 0; r < 4; ++r) {
        int orow = lk*4 + r;
        float s_tot = redS[0][orow] + redS[1][orow];
        float q_tot = redQ[0][orow] + redQ[1][orow];
        float mean = s_tot * (1.f/128.f);
        float var  = q_tot * (1.f/128.f) - mean*mean;
        float rstd = rsqrtf(var + 1e-5f);
        f32x4 po = (f32x4){0.f,0.f,0.f,0.f};
        #pragma unroll
        for (int c = 0; c < 4; ++c) {
            float v = acc[c][r] + bc[c];
            float o = fmaxf((v-mean)*rstd*gc[c] + bbc[c], 0.f);
            po += o * hwc[c];
        }
        #pragma unroll
        for (int off = 1; off < 16; off <<= 1) {
            po.x += __shfl_xor(po.x, off, 64);
            po.y += __shfl_xor(po.y, off, 64);
            po.z += __shfl_xor(po.z, off, 64);
            po.w += __shfl_xor(po.w, off, 64);
        }
        poarr[r] = po;
        if (w == 1 && lr == 0) redP[orow] = po;
    }
    __syncthreads();

    if (w == 0 && lr == 0) {
        f32x4 hb4 = *(const f32x4*)a.hb;
        #pragma unroll
        for (int r = 0; r < 4; ++r) {
            int orow = lk*4 + r;
            if (orow < 8) {                      // D rows 8..15 (duplicates) discarded
                f32x4 res = poarr[r] + redP[orow] + hb4;
                *(f32x4*)(a.out + (size_t)(rowbase + orow)*4) = res;
            }
        }
    }
}

extern "C" void kernel_launch(void* const* d_in, const int* in_sizes, int n_in,
                              void* d_out, int out_size, void* d_ws, size_t ws_size,
                              hipStream_t stream)
{
    KArgs a;
    a.x    = (const float*)d_in[0];
    a.ea   = (const float*)d_in[1];
    a.src  = (const int*)d_in[2];            // edge_index[0] = first E entries
    a.ew0  = (const float*)d_in[3];
    a.eb0  = (const float*)d_in[4];
    a.pw0  = (const float*)d_in[5];
    a.pb0  = (const float*)d_in[6];
    a.qw0  = (const float*)d_in[7];
    a.qb0  = (const float*)d_in[8];
    a.lw0  = (const float*)d_in[9];
    a.lb0  = (const float*)d_in[10];
    a.g0   = (const float*)d_in[11];
    a.bl0  = (const float*)d_in[12];
    a.ew1  = (const float*)d_in[13];
    a.eb1  = (const float*)d_in[14];
    a.pw1  = (const float*)d_in[15];
    a.pb1  = (const float*)d_in[16];
    a.qw1  = (const float*)d_in[17];
    a.qb1  = (const float*)d_in[18];
    a.lw1  = (const float*)d_in[19];
    a.lb1  = (const float*)d_in[20];
    a.g1   = (const float*)d_in[21];
    a.bl1  = (const float*)d_in[22];
    a.hw   = (const float*)d_in[23];
    a.hb   = (const float*)d_in[24];
    a.ws   = (float*)d_ws;
    a.out  = (float*)d_out;

    k_prep<<<2995, 256, 0, stream>>>(a);
    k_mid <<< 625, 256, 0, stream>>>(a);
    k_tail<<<2500, 128, 0, stream>>>(a);
}

// Round 11
// 99.348 us; speedup vs baseline: 1.4688x; 1.4688x over previous
//
#include <hip/hip_runtime.h>
#include <math.h>

#define N_NODES 20000
#define N_EDGES 160000

typedef unsigned short ushort_t;
typedef __attribute__((ext_vector_type(8))) short short8v;   // 8 bf16 = 4 VGPR
typedef __attribute__((ext_vector_type(4))) float f32x4;

// ---- workspace layout (float offsets) ----
#define WS_We0  0         // [8][16] f32
#define WS_b0m  128       // [16]
#define WS_W0   256       // [80][128] f32 (folded)
#define WS_b0   10496     // [128]
#define WS_We1  10624     // [8][128] f32
#define WS_b1m  11648     // [128]
#define WS_b1   11776     // [128]
#define WS_WP1  11904     // bf16 frags 81920 -> 40960 f  (B for gemm1, K=640)
#define WS_WPTU 52864     // bf16 frags 32768 -> 16384 f  (B for t1/u1)
#define WS_t0   69248     // f32 [20000][16]
#define WS_u0   389248    // f32 [20000][16]
#define WS_h0b  709248    // bf16 [20000][128] = 1,280,000 f
#define WS_t1   1989248   // f32 [20000][128]
#define WS_u1   4549248   // bf16 [20000][128] (u1b)
#define WS_A0   7109248   // f32 [20000][80]  (dead after gemm0 phase)
#define WS_A1   7109248   // bf16 [20000][512] OVERLAYS A0; ends 12,229,248
// end 12,229,248 f = 48.9 MB

__device__ inline ushort_t f2bf(float f) {   // round-to-nearest-even f32->bf16
    union { float f; unsigned u; } v; v.f = f;
    unsigned r = v.u + 0x7FFFu + ((v.u >> 16) & 1u);
    return (ushort_t)(r >> 16);
}
__device__ inline float bf2f(short s) {
    union { unsigned u; float f; } v; v.u = ((unsigned)(ushort_t)s) << 16; return v.f;
}

// ================= phase 0: weight folds + direct frag packing + t0/u0 ================
__device__ __attribute__((noinline)) void prep_item(
    int tid, const float* __restrict__ x,
    const float* __restrict__ ew0, const float* __restrict__ eb0,
    const float* __restrict__ pw0, const float* __restrict__ pb0,
    const float* __restrict__ qw0, const float* __restrict__ qb0,
    const float* __restrict__ lw0, const float* __restrict__ lb0,
    const float* __restrict__ ew1, const float* __restrict__ eb1,
    const float* __restrict__ pw1, const float* __restrict__ pb1,
    const float* __restrict__ qw1, const float* __restrict__ qb1,
    const float* __restrict__ lw1, const float* __restrict__ lb1,
    float* __restrict__ ws)
{
    if (tid < 81920) {                 // W1 fold -> WP1 bf16 frag: [640][128]
        int r = tid >> 7, o = tid & 127;
        float acc = 0.f;
        for (int h = 0; h < 128; ++h) {
            float qr;
            if (r < 128) qr = qw1[r*128 + h];
            else {
                int s = r - 128;
                qr = qw1[(128+s)*128+h] + qw1[(640+s)*128+h] + qw1[(1152+s)*128+h];
            }
            acc += qr * lw1[h*128 + o];
        }
        int ct = o >> 4, ks = r >> 5;
        int l = (o & 15) | (((r >> 3) & 3) << 4);
        ((ushort_t*)(ws + WS_WP1))[(size_t)(((ct*20 + ks)*64) + l)*8 + (r & 7)] = f2bf(acc);
    } else if (tid < 82048) {          // b1 = qb1@lw1 + lb1
        int o = tid - 81920;
        float acc = lb1[o];
        for (int h = 0; h < 128; ++h) acc += qb1[h] * lw1[h*128 + o];
        ws[WS_b1 + o] = acc;
    } else if (tid < 92288) {          // W0 fold f32 [80][128]
        int idx = tid - 82048; int r = idx >> 7, o = idx & 127;
        float acc = 0.f;
        for (int h = 0; h < 128; ++h) {
            float qr;
            if (r < 16) qr = qw0[r*128 + h];
            else {
                int s = r - 16;
                qr = qw0[(16+s)*128+h] + qw0[(80+s)*128+h] + qw0[(144+s)*128+h];
            }
            acc += qr * lw0[h*128 + o];
        }
        ws[WS_W0 + idx] = acc;
    } else if (tid < 92416) {          // b0 = qb0@lw0 + lb0
        int o = tid - 92288;
        float acc = lb0[o];
        for (int h = 0; h < 128; ++h) acc += qb0[h] * lw0[h*128 + o];
        ws[WS_b0 + o] = acc;
    } else if (tid < 93440) {          // We1 = ew1 @ pw1_c  [8][128] f32
        int idx = tid - 92416; int c = idx >> 7, f = idx & 127;
        float acc = 0.f;
        for (int k = 0; k < 128; ++k) acc += ew1[c*128 + k] * pw1[(256+k)*128 + f];
        ws[WS_We1 + idx] = acc;
    } else if (tid < 93568) {          // b1m = eb1@pw1_c + pb1
        int f = tid - 93440;
        float acc = pb1[f];
        for (int k = 0; k < 128; ++k) acc += eb1[k] * pw1[(256+k)*128 + f];
        ws[WS_b1m + f] = acc;
    } else if (tid < 93696) {          // We0 = ew0 @ pw0_c  [8][16]
        int idx = tid - 93568; int c = idx >> 4, f = idx & 15;
        float acc = 0.f;
        for (int k = 0; k < 16; ++k) acc += ew0[c*16 + k] * pw0[(32+k)*16 + f];
        ws[WS_We0 + idx] = acc;
    } else if (tid < 93712) {          // b0m = eb0@pw0_c + pb0
        int f = tid - 93696;
        float acc = pb0[f];
        for (int k = 0; k < 16; ++k) acc += eb0[k] * pw0[(32+k)*16 + f];
        ws[WS_b0m + f] = acc;
    } else if (tid < 126480) {         // WPTU direct pack from pw1 rows 0..255
        int idx = tid - 93712;
        int r = idx >> 7, o = idx & 127;
        int part = r >> 7, rk = r & 127;
        int ct = part*8 + (o >> 4);
        int l = (o & 15) | (((rk >> 3) & 3) << 4);
        ((ushort_t*)(ws + WS_WPTU))[(size_t)(((ct*4 + (rk >> 5))*64) + l)*8 + (rk & 7)]
            = f2bf(pw1[r*128 + o]);
    } else if (tid < 446480) {         // t0 = x @ pw0_a  [20000][16]
        int idx = tid - 126480; int i = idx >> 4, f = idx & 15;
        float acc = 0.f;
        for (int k = 0; k < 16; ++k) acc += x[i*16 + k] * pw0[k*16 + f];
        ws[WS_t0 + idx] = acc;
    } else if (tid < 766480) {         // u0 = x @ pw0_b  [20000][16]
        int idx = tid - 446480; int i = idx >> 4, f = idx & 15;
        float acc = 0.f;
        for (int k = 0; k < 16; ++k) acc += x[i*16 + k] * pw0[(16+k)*16 + f];
        ws[WS_u0 + idx] = acc;
    }
}

// ================= phase 1: layer-0 gather + aggregate -> A0 (f32)  [R8-proven] =================
__device__ __attribute__((noinline)) void agg0_tile(
    int tile, int t, const float* __restrict__ x, const float* __restrict__ ea,
    const int* __restrict__ src, float* __restrict__ ws)
{
    static __shared__ float ea_s0[16*8*8];   // [n][k][c]
    static __shared__ int   src_s0[16*8];
    static __shared__ float We0_s0[128];
    static __shared__ float b0m_s0[16];
    const int i0 = tile * 16;
    __syncthreads();            // LDS reuse guard

    for (int idx = t; idx < 1024; idx += 256) {
        int k = idx >> 7; int rem = idx & 127; int n = rem >> 3, c = rem & 7;
        ea_s0[(n*8 + k)*8 + c] = ea[(i0 + n + k*N_NODES)*8 + c];
    }
    if (t < 128) {
        int k = t >> 4, n = t & 15;
        src_s0[n*8 + k] = src[i0 + n + k*N_NODES];
        We0_s0[t] = ws[WS_We0 + t];
    }
    if (t < 16) b0m_s0[t] = ws[WS_b0m + t];
    __syncthreads();

    const int n = t >> 4, f = t & 15;
    const int i = i0 + n;
    float base = ws[WS_t0 + i*16 + f] + b0m_s0[f];
    float s = 0.f, q = 0.f, mx = -1e30f, mn = 1e30f;
    for (int k = 0; k < 8; ++k) {
        int sj = src_s0[n*8 + k];
        float m = base + ws[WS_u0 + sj*16 + f];
        #pragma unroll
        for (int c = 0; c < 8; ++c) m += ea_s0[(n*8+k)*8 + c] * We0_s0[c*16 + f];
        s += m; q += m*m; mx = fmaxf(mx, m); mn = fminf(mn, m);
    }
    float mean = s * 0.125f, mean2 = q * 0.125f;
    float sd = sqrtf(fmaxf(mean2 - mean*mean, 0.f) + 1e-5f);
    float* A0 = ws + WS_A0 + (size_t)i * 80;
    A0[f]      = x[i*16 + f];
    A0[16 + f] = mean;
    A0[32 + f] = mx;
    A0[48 + f] = mn;
    A0[64 + f] = sd;
}

// ================= phase 2: h0b = bf16(relu(LN(A0 @ W0 + b0)))  [R8-proven] =================
__device__ __attribute__((noinline)) void gemm0_tile(
    int tile, int t, const float* __restrict__ g0, const float* __restrict__ bln0,
    float* __restrict__ ws)
{
    static __shared__ float As[32][81];
    const int r0 = tile * 32;
    __syncthreads();            // orders prior global writes + LDS reuse
    const float* A = ws + WS_A0 + (size_t)r0 * 80;
    for (int idx = t; idx < 32*80; idx += 256) {
        int r = idx / 80, k = idx - r*80;
        As[r][k] = A[idx];
    }
    __syncthreads();
    const int tc = t & 31, tr = t >> 5;
    const int c0 = tc * 4;
    float acc[4][4] = {};
    const float* W = ws + WS_W0;
    #pragma unroll 4
    for (int k = 0; k < 80; ++k) {
        float4 b = *(const float4*)(W + k*128 + c0);
        #pragma unroll
        for (int rr = 0; rr < 4; ++rr) {
            float a = As[tr*4 + rr][k];
            acc[rr][0] += a*b.x; acc[rr][1] += a*b.y;
            acc[rr][2] += a*b.z; acc[rr][3] += a*b.w;
        }
    }
    float4 bias = *(const float4*)(ws + WS_b0 + c0);
    float4 g  = *(const float4*)(g0 + c0);
    float4 bb = *(const float4*)(bln0 + c0);
    ushort_t* h0b = (ushort_t*)(ws + WS_h0b);
    #pragma unroll
    for (int rr = 0; rr < 4; ++rr) {
        float v0 = acc[rr][0] + bias.x, v1 = acc[rr][1] + bias.y;
        float v2 = acc[rr][2] + bias.z, v3 = acc[rr][3] + bias.w;
        float sum = v0+v1+v2+v3;
        float sq  = v0*v0+v1*v1+v2*v2+v3*v3;
        #pragma unroll
        for (int off = 1; off < 32; off <<= 1) {
            sum += __shfl_xor(sum, off, 64);
            sq  += __shfl_xor(sq,  off, 64);
        }
        float mean = sum * (1.f/128.f);
        float var  = sq  * (1.f/128.f) - mean*mean;
        float rstd = rsqrtf(var + 1e-5f);
        ushort4 ob;
        ob.x = f2bf(fmaxf((v0-mean)*rstd*g.x + bb.x, 0.f));
        ob.y = f2bf(fmaxf((v1-mean)*rstd*g.y + bb.y, 0.f));
        ob.z = f2bf(fmaxf((v2-mean)*rstd*g.z + bb.z, 0.f));
        ob.w = f2bf(fmaxf((v3-mean)*rstd*g.w + bb.w, 0.f));
        *(ushort4*)(h0b + (size_t)(r0 + tr*4 + rr)*128 + c0) = ob;
    }
}

// ========== phase 3: t1 (f32) | u1 (bf16) half-tile = h0 @ pw1[a|b]  [R8-proven] ==========
__device__ __attribute__((noinline)) void tu1_half(
    int tile, int part, int lane, float* __restrict__ ws)
{
    const int rowbase = tile * 16;
    const ushort_t* h0b = (const ushort_t*)(ws + WS_h0b);
    const ushort_t* WP  = (const ushort_t*)(ws + WS_WPTU);
    const int lr = lane & 15, lk = lane >> 4;
    const size_t arow = rowbase + lr;
    f32x4 acc[8];
    #pragma unroll
    for (int c = 0; c < 8; ++c) acc[c] = (f32x4){0.f,0.f,0.f,0.f};

    #pragma unroll
    for (int ks = 0; ks < 4; ++ks) {
        short8v a = *(const short8v*)(h0b + arow*128 + ks*32 + lk*8);
        #pragma unroll
        for (int c = 0; c < 8; ++c) {
            short8v b = *(const short8v*)(WP + ((size_t)((part*8 + c)*4 + ks)*64 + lane)*8);
            acc[c] = __builtin_amdgcn_mfma_f32_16x16x32_bf16(a, b, acc[c], 0, 0, 0);
        }
    }
    if (part == 0) {                    // t1 stays f32
        float* t1 = ws + WS_t1;
        #pragma unroll
        for (int c = 0; c < 8; ++c) {
            int cb = c*16 + lr;
            #pragma unroll
            for (int r = 0; r < 4; ++r) {
                int row = rowbase + lk*4 + r;  // C/D: col=lane&15, row=(lane>>4)*4+reg
                t1[(size_t)row*128 + cb] = acc[c][r];
            }
        }
    } else {                            // u1 -> bf16
        ushort_t* u1b = (ushort_t*)(ws + WS_u1);
        #pragma unroll
        for (int c = 0; c < 8; ++c) {
            int cb = c*16 + lr;
            #pragma unroll
            for (int r = 0; r < 4; ++r) {
                int row = rowbase + lk*4 + r;
                u1b[(size_t)row*128 + cb] = f2bf(acc[c][r]);
            }
        }
    }
}

// ======== phase 4: layer-1 aggregate -> A1 bf16 (16 nodes, 256 thr)  [R8-proven] ========
__device__ __attribute__((noinline)) void agg1_tile(
    int tile, int t, const float* __restrict__ ea, const int* __restrict__ src,
    float* __restrict__ ws)
{
    static __shared__ float ea_s1[16*8*8];
    static __shared__ int   src_s1[128];
    static __shared__ float We1_s1[1024];
    static __shared__ float b1m_s1[128];
    const int i0 = tile * 16;
    __syncthreads();            // LDS reuse guard

    for (int idx = t; idx < 1024; idx += 256) {
        int k = idx >> 7; int rem = idx & 127; int n = rem >> 3, c = rem & 7;
        ea_s1[(n*8 + k)*8 + c] = ea[(i0 + n + k*N_NODES)*8 + c];
    }
    if (t < 128) {
        int k = t >> 4, n = t & 15;
        src_s1[n*8 + k] = src[i0 + n + k*N_NODES];
    }
    for (int idx = t; idx < 1024; idx += 256) We1_s1[idx] = ws[WS_We1 + idx];
    if (t < 128) b1m_s1[t] = ws[WS_b1m + t];
    __syncthreads();

    const int n = t >> 4, f0 = (t & 15) * 8;
    const int i = i0 + n;
    const ushort_t* u1b = (const ushort_t*)(ws + WS_u1);
    float base[8], sm[8], sq[8], mx[8], mn[8];
    #pragma unroll
    for (int e = 0; e < 8; ++e) {
        base[e] = ws[WS_t1 + (size_t)i*128 + f0 + e] + b1m_s1[f0 + e];
        sm[e] = 0.f; sq[e] = 0.f; mx[e] = -1e30f; mn[e] = 1e30f;
    }
    for (int k = 0; k < 8; ++k) {
        int sj = src_s1[n*8 + k];
        short8v uv = *(const short8v*)(u1b + (size_t)sj*128 + f0);   // 16B gather
        float m[8];
        #pragma unroll
        for (int e = 0; e < 8; ++e) m[e] = base[e] + bf2f(uv[e]);
        #pragma unroll
        for (int c = 0; c < 8; ++c) {
            float a = ea_s1[(n*8 + k)*8 + c];
            #pragma unroll
            for (int e = 0; e < 8; ++e) m[e] += a * We1_s1[c*128 + f0 + e];
        }
        #pragma unroll
        for (int e = 0; e < 8; ++e) {
            sm[e] += m[e]; sq[e] += m[e]*m[e];
            mx[e] = fmaxf(mx[e], m[e]); mn[e] = fminf(mn[e], m[e]);
        }
    }
    ushort_t* A1 = (ushort_t*)(ws + WS_A1);
    short8v vm, vx, vn, vs;
    #pragma unroll
    for (int e = 0; e < 8; ++e) {
        float mean = sm[e]*0.125f, m2 = sq[e]*0.125f;
        float sd = sqrtf(fmaxf(m2 - mean*mean, 0.f) + 1e-5f);
        vm[e] = (short)f2bf(mean);
        vx[e] = (short)f2bf(mx[e]);
        vn[e] = (short)f2bf(mn[e]);
        vs[e] = (short)f2bf(sd);
    }
    size_t b = (size_t)i*512 + f0;
    *(short8v*)(A1 + b)       = vm;
    *(short8v*)(A1 + b + 128) = vx;
    *(short8v*)(A1 + b + 256) = vn;
    *(short8v*)(A1 + b + 384) = vs;
}

// ======================= args struct =======================
struct KArgs {
    const float *x, *ea; const int* src;
    const float *ew0,*eb0,*pw0,*pb0,*qw0,*qb0,*lw0,*lb0,*g0,*bl0;
    const float *ew1,*eb1,*pw1,*pb1,*qw1,*qb1,*lw1,*lb1,*g1,*bl1;
    const float *hw,*hb;
    float* ws; float* out;
};

// ============ launch 1: prep ============
__global__ __launch_bounds__(256) void k_prep(KArgs a) {
    int tid = blockIdx.x*256 + threadIdx.x;
    prep_item(tid, a.x, a.ew0, a.eb0, a.pw0, a.pb0, a.qw0, a.qb0, a.lw0, a.lb0,
              a.ew1, a.eb1, a.pw1, a.pb1, a.qw1, a.qb1, a.lw1, a.lb1, a.ws);
}

// ============ launch 2: agg0 x2 -> gemm0 -> tu1 x4 (32 rows/block)  [R8-proven] ============
__global__ __launch_bounds__(256) void k_mid(KArgs a) {
    const int b = blockIdx.x, t = threadIdx.x;
    agg0_tile(b*2,     t, a.x, a.ea, a.src, a.ws);
    agg0_tile(b*2 + 1, t, a.x, a.ea, a.src, a.ws);
    gemm0_tile(b, t, a.g0, a.bl0, a.ws);       // entry-sync orders A0 writes
    __syncthreads();                            // h0b global writes -> tu1 reads
    const int w = t >> 6;
    tu1_half(b*2 + (w >> 1), w & 1, t & 63, a.ws);
}

// ============ launch 3: standalone agg1 (1250 x 256, full gather TLP) ============
__global__ __launch_bounds__(256) void k_agg1(KArgs a) {
    agg1_tile(blockIdx.x, threadIdx.x, a.ea, a.src, a.ws);
}

// ===== launch 4: 32 rows/block, 4 waves: rt=w>>1, col-half=w&1; pipelined MFMA K=640 =====
// All inputs from prior launches; LN/head epilogue = R10's value-proven 2-partial pattern.
__global__ __launch_bounds__(256) void k_gemm1(KArgs a) {
    static __shared__ float redS[2][2][16], redQ[2][2][16];
    static __shared__ f32x4 redP[2][16];
    const int b = blockIdx.x, t = threadIdx.x;
    float* ws = a.ws;
    const int w = t >> 6, lane = t & 63;
    const int rt = w >> 1, chalf = w & 1;
    const int lr = lane & 15, lk = lane >> 4;
    const int rowbase = b * 32;
    const int row = rowbase + rt*16 + lr;
    const ushort_t* h0b = (const ushort_t*)(ws + WS_h0b);
    const ushort_t* A1  = (const ushort_t*)(ws + WS_A1);
    const ushort_t* WP  = (const ushort_t*)(ws + WS_WP1);
    const size_t aoff_h = (size_t)row*128 + lk*8;   // + ksu*32        (ksu 0..3)
    const size_t aoff_a = (size_t)row*512 + lk*8;   // + (ksu-4)*32    (ksu 4..19)

    f32x4 acc[4];
    #pragma unroll
    for (int c = 0; c < 4; ++c) acc[c] = (f32x4){0.f,0.f,0.f,0.f};

    // manual 1-deep software pipeline: issue next iteration's A+B loads before MFMAs
    short8v aN = *(const short8v*)(h0b + aoff_h);
    short8v bN0 = *(const short8v*)(WP + (size_t)(((chalf*4+0)*20)*64 + lane)*8);
    short8v bN1 = *(const short8v*)(WP + (size_t)(((chalf*4+1)*20)*64 + lane)*8);
    short8v bN2 = *(const short8v*)(WP + (size_t)(((chalf*4+2)*20)*64 + lane)*8);
    short8v bN3 = *(const short8v*)(WP + (size_t)(((chalf*4+3)*20)*64 + lane)*8);
    #pragma unroll
    for (int ksu = 0; ksu < 20; ++ksu) {
        short8v av = aN, bv0 = bN0, bv1 = bN1, bv2 = bN2, bv3 = bN3;
        if (ksu < 19) {
            const int kn = ksu + 1;
            aN = (kn < 4) ? *(const short8v*)(h0b + aoff_h + kn*32)
                          : *(const short8v*)(A1 + aoff_a + (kn-4)*32);
            bN0 = *(const short8v*)(WP + (size_t)(((chalf*4+0)*20 + kn)*64 + lane)*8);
            bN1 = *(const short8v*)(WP + (size_t)(((chalf*4+1)*20 + kn)*64 + lane)*8);
            bN2 = *(const short8v*)(WP + (size_t)(((chalf*4+2)*20 + kn)*64 + lane)*8);
            bN3 = *(const short8v*)(WP + (size_t)(((chalf*4+3)*20 + kn)*64 + lane)*8);
        }
        acc[0] = __builtin_amdgcn_mfma_f32_16x16x32_bf16(av, bv0, acc[0], 0, 0, 0);
        acc[1] = __builtin_amdgcn_mfma_f32_16x16x32_bf16(av, bv1, acc[1], 0, 0, 0);
        acc[2] = __builtin_amdgcn_mfma_f32_16x16x32_bf16(av, bv2, acc[2], 0, 0, 0);
        acc[3] = __builtin_amdgcn_mfma_f32_16x16x32_bf16(av, bv3, acc[3], 0, 0, 0);
    }

    float bc[4], gc[4], bbc[4]; f32x4 hwc[4];
    #pragma unroll
    for (int c = 0; c < 4; ++c) {
        int col = (chalf*4 + c)*16 + lr;
        bc[c]  = ws[WS_b1 + col];
        gc[c]  = a.g1[col];
        bbc[c] = a.bl1[col];
        hwc[c] = *(const f32x4*)(a.hw + col*4);
    }

    // pass 1: per-wave partial LN sums over its 64 cols
    #pragma unroll
    for (int r = 0; r < 4; ++r) {
        float s = 0.f, q = 0.f;
        #pragma unroll
        for (int c = 0; c < 4; ++c) {
            float v = acc[c][r] + bc[c];
            s += v; q += v*v;
        }
        #pragma unroll
        for (int off = 1; off < 16; off <<= 1) {
            s += __shfl_xor(s, off, 64);
            q += __shfl_xor(q, off, 64);
        }
        if (lr == 0) { redS[rt][chalf][lk*4 + r] = s; redQ[rt][chalf][lk*4 + r] = q; }
    }
    __syncthreads();

    // pass 2: full LN + relu + head partial over own cols
    f32x4 poarr[4];
    #pragma unroll
    for (int r = 0; r < 4; ++r) {
        int orow = lk*4 + r;
        float s_tot = redS[rt][0][orow] + redS[rt][1][orow];
        float q_tot = redQ[rt][0][orow] + redQ[rt][1][orow];
        float mean = s_tot * (1.f/128.f);
        float var  = q_tot * (1.f/128.f) - mean*mean;
        float rstd = rsqrtf(var + 1e-5f);
        f32x4 po = (f32x4){0.f,0.f,0.f,0.f};
        #pragma unroll
        for (int c = 0; c < 4; ++c) {
            float v = acc[c][r] + bc[c];
            float o = fmaxf((v-mean)*rstd*gc[c] + bbc[c], 0.f);
            po += o * hwc[c];
        }
        #pragma unroll
        for (int off = 1; off < 16; off <<= 1) {
            po.x += __shfl_xor(po.x, off, 64);
            po.y += __shfl_xor(po.y, off, 64);
            po.z += __shfl_xor(po.z, off, 64);
            po.w += __shfl_xor(po.w, off, 64);
        }
        poarr[r] = po;
        if (chalf == 1 && lr == 0) redP[rt][orow] = po;
    }
    __syncthreads();

    if (chalf == 0 && lr == 0) {
        f32x4 hb4 = *(const f32x4*)a.hb;
        #pragma unroll
        for (int r = 0; r < 4; ++r) {
            int orow = lk*4 + r;
            f32x4 res = poarr[r] + redP[rt][orow] + hb4;
            *(f32x4*)(a.out + (size_t)(rowbase + rt*16 + orow)*4) = res;
        }
    }
}

extern "C" void kernel_launch(void* const* d_in, const int* in_sizes, int n_in,
                              void* d_out, int out_size, void* d_ws, size_t ws_size,
                              hipStream_t stream)
{
    KArgs a;
    a.x    = (const float*)d_in[0];
    a.ea   = (const float*)d_in[1];
    a.src  = (const int*)d_in[2];            // edge_index[0] = first E entries
    a.ew0  = (const float*)d_in[3];
    a.eb0  = (const float*)d_in[4];
    a.pw0  = (const float*)d_in[5];
    a.pb0  = (const float*)d_in[6];
    a.qw0  = (const float*)d_in[7];
    a.qb0  = (const float*)d_in[8];
    a.lw0  = (const float*)d_in[9];
    a.lb0  = (const float*)d_in[10];
    a.g0   = (const float*)d_in[11];
    a.bl0  = (const float*)d_in[12];
    a.ew1  = (const float*)d_in[13];
    a.eb1  = (const float*)d_in[14];
    a.pw1  = (const float*)d_in[15];
    a.pb1  = (const float*)d_in[16];
    a.qw1  = (const float*)d_in[17];
    a.qb1  = (const float*)d_in[18];
    a.lw1  = (const float*)d_in[19];
    a.lb1  = (const float*)d_in[20];
    a.g1   = (const float*)d_in[21];
    a.bl1  = (const float*)d_in[22];
    a.hw   = (const float*)d_in[23];
    a.hb   = (const float*)d_in[24];
    a.ws   = (float*)d_ws;
    a.out  = (float*)d_out;

    k_prep <<<2995, 256, 0, stream>>>(a);
    k_mid  <<< 625, 256, 0, stream>>>(a);
    k_agg1 <<<1250, 256, 0, stream>>>(a);
    k_gemm1<<< 625, 256, 0, stream>>>(a);
}